// Round 17
// baseline (99.488 us; speedup 1.0000x reference)
//
#include <hip/hip_runtime.h>
#include <math.h>

#define NEG_SLOPE 0.2f
#define EPS_F 1e-16f
#define CIN 128
#define HC 64
#define BSH 6              // bucket shift: 64 nodes per bucket
#define BNODES 64
#define NBKT 2048          // bucket count (tgt >> 6), max node 131071 (N < 2^17)
#define PBLK 256           // partition blocks
#define CSR_CAP 2048       // LDS csr capacity per bucket (avg ~1025, max ~1200)
#define RCAP 8             // per-thread register edge cache

typedef _Float16 f16;
typedef _Float16 f16x8 __attribute__((ext_vector_type(8)));
typedef float f32x4  __attribute__((ext_vector_type(4)));

// ---- fused: P3 partition (blocks [0,PBLK)) + projection (rest) ------------
// proj: 128 rows/block, two software-pipelined 64-row tiles (tile-B loads
// issued under tile-A's epilogue VALU). offsT transposed for p4 coalescing.
__global__ __launch_bounds__(256) void proj_p3(
    const float* __restrict__ x, const float* __restrict__ W,
    const float* __restrict__ att, f16* __restrict__ h,
    float* __restrict__ asrc, float* __restrict__ atgt, int N,
    const int* __restrict__ src, const int* __restrict__ tgt,
    int* __restrict__ offsT, int* __restrict__ pairs, int E, int EPB)
{
    __shared__ __align__(16) char smem[HC * (CIN + 8) * 2];   // 17408 B union

    if ((int)blockIdx.x < PBLK) {
        // ---- P3 role ----
        int* lh    = (int*)smem;          // [2048] counts -> cursors (8 KB)
        int* scanP = lh + NBKT;           // [256]
        int pb = blockIdx.x, tid = threadIdx.x;
        for (int i = tid; i < NBKT; i += 256) lh[i] = 0;
        __syncthreads();
        int e0 = pb * EPB, e1 = min(E, e0 + EPB), sz = e1 - e0;
        for (int e = e0 + tid; e < e1; e += 256)
            atomicAdd(&lh[((unsigned)tgt[e]) >> BSH], 1);
        __syncthreads();
        // exclusive scan of 2048 bins: 8 bins/thread + 256-wide Hillis-Steele
        int b8 = tid * 8;
        int v[8], s8 = 0;
#pragma unroll
        for (int i = 0; i < 8; ++i) { v[i] = lh[b8 + i]; s8 += v[i]; }
        scanP[tid] = s8;
        __syncthreads();
        for (int d = 1; d < 256; d <<= 1) {
            int t = (tid >= d) ? scanP[tid - d] : 0;
            __syncthreads();
            scanP[tid] += t;
            __syncthreads();
        }
        int base = scanP[tid] - s8;
        __syncthreads();
        {
            int run = base;
#pragma unroll
            for (int i = 0; i < 8; ++i) {
                lh[b8 + i] = run;
                offsT[(size_t)(b8 + i) * PBLK + pb] = run;   // transposed
                run += v[i];
            }
        }
        if (tid == 0) offsT[(size_t)NBKT * PBLK + pb] = sz;
        __syncthreads();
        // scatter within own contiguous region (L2 absorbs in-window RMW)
        for (int e = e0 + tid; e < e1; e += 256) {
            int t = tgt[e];
            int r = atomicAdd(&lh[((unsigned)t) >> BSH], 1);
            pairs[e0 + r] = src[e] | ((t & (BNODES - 1)) << 17);
        }
        return;
    }

    // ---- proj role: 128 rows per block ----
    f16 (*sWt)[CIN + 8] = (f16(*)[CIN + 8])smem;
    int rowBase = ((int)blockIdx.x - PBLK) * 128;
    for (int i = threadIdx.x; i < CIN * HC; i += 256) {
        int k = i >> 6, c = i & 63;
        sWt[c][k] = (f16)W[i];
    }
    __syncthreads();

    int lane = threadIdx.x & 63;
    int wv   = threadIdx.x >> 6;
    int mrow = lane & 15, g = lane >> 4;
    int r16a = rowBase + wv * 16;
    int r16b = rowBase + 64 + wv * 16;

    f16x8 bfrag[4][4];
#pragma unroll
    for (int nt = 0; nt < 4; ++nt)
#pragma unroll
        for (int kc = 0; kc < 4; ++kc)
            bfrag[nt][kc] = *reinterpret_cast<const f16x8*>(&sWt[nt * 16 + mrow][kc * 32 + g * 8]);

#define LOAD_TILE(XA, R16)                                                    \
    {                                                                         \
        int arow = (R16) + mrow;                                              \
        const float* xr = x + (size_t)(arow < N ? arow : N - 1) * CIN;        \
        _Pragma("unroll")                                                     \
        for (int kc = 0; kc < 4; ++kc) {                                      \
            XA[kc][0] = *reinterpret_cast<const float4*>(xr + kc * 32 + g * 8);     \
            XA[kc][1] = *reinterpret_cast<const float4*>(xr + kc * 32 + g * 8 + 4); \
        }                                                                     \
    }

#define MFMA_TILE(XA, ACC)                                                    \
    _Pragma("unroll")                                                         \
    for (int kc = 0; kc < 4; ++kc) {                                          \
        f16x8 a;                                                              \
        a[0] = (f16)XA[kc][0].x; a[1] = (f16)XA[kc][0].y;                     \
        a[2] = (f16)XA[kc][0].z; a[3] = (f16)XA[kc][0].w;                     \
        a[4] = (f16)XA[kc][1].x; a[5] = (f16)XA[kc][1].y;                     \
        a[6] = (f16)XA[kc][1].z; a[7] = (f16)XA[kc][1].w;                     \
        _Pragma("unroll")                                                     \
        for (int nt = 0; nt < 4; ++nt)                                        \
            ACC[nt] = __builtin_amdgcn_mfma_f32_16x16x32_f16(a, bfrag[nt][kc], ACC[nt], 0, 0, 0); \
    }

#define EPILOGUE(ACC, R16)                                                    \
    _Pragma("unroll")                                                         \
    for (int nt = 0; nt < 4; ++nt) {                                          \
        int c = nt * 16 + mrow;                                               \
        float as_w = att[(c >> 3) * 16 + (c & 7)];                            \
        float at_w = att[(c >> 3) * 16 + 8 + (c & 7)];                        \
        _Pragma("unroll")                                                     \
        for (int q = 0; q < 4; ++q) {                                         \
            int n = (R16) + g * 4 + q;                                        \
            float v = ACC[nt][q];                                             \
            if (n < N) h[(size_t)n * HC + c] = (f16)v;                        \
            float vs = v * as_w, vt = v * at_w;                               \
            vs += __shfl_xor(vs, 1); vs += __shfl_xor(vs, 2); vs += __shfl_xor(vs, 4); \
            vt += __shfl_xor(vt, 1); vt += __shfl_xor(vt, 2); vt += __shfl_xor(vt, 4); \
            if ((lane & 7) == 0 && n < N) {                                   \
                asrc[n * 8 + (c >> 3)] = vs;                                  \
                atgt[n * 8 + (c >> 3)] = vt;                                  \
            }                                                                 \
        }                                                                     \
    }

    // tile A: load + MFMA
    float4 xaA[4][2];
    LOAD_TILE(xaA, r16a)
    f32x4 accA[4] = {};
    MFMA_TILE(xaA, accA)

    // tile B: issue loads now — latency hides under tile A's epilogue VALU
    float4 xaB[4][2];
    LOAD_TILE(xaB, r16b)

    EPILOGUE(accA, r16a)

    f32x4 accB[4] = {};
    MFMA_TILE(xaB, accB)
    EPILOGUE(accB, r16b)
}

// ---- fused P4 + gather: reg-cached single-pass segments, shfl scans -------
__global__ __launch_bounds__(256) void p4_gather(
    const int* __restrict__ pairs, const int* __restrict__ offsT,
    const f16* __restrict__ h, const float* __restrict__ asrc,
    const float* __restrict__ atgt, const float* __restrict__ bias,
    float* __restrict__ out, int N, int E, int EPB)
{
    __shared__ int segB[PBLK], segL[PBLK];
    __shared__ int hist[BNODES], scanS[BNODES], fill[BNODES], order[BNODES];
    __shared__ int h2[64], s2[64];
    __shared__ int wtot[4];
    __shared__ int csrL[CSR_CAP];

    int b   = blockIdx.x;
    int tid = threadIdx.x;
    int bN0 = b << BSH;
    int lane = tid & 63, wid = tid >> 6;

    // coalesced descriptor reads (transposed offs)
    int o0 = offsT[(size_t)b * PBLK + tid];
    int o1 = offsT[(size_t)(b + 1) * PBLK + tid];
    int myB = tid * EPB + o0;
    int myL = o1 - o0;
    segB[tid] = myB;
    segL[tid] = myL;

    // 256-wide exclusive scan of myL: shfl within wave + cross-wave fixup
    int v = myL;
#pragma unroll
    for (int d = 1; d < 64; d <<= 1) {
        int t = __shfl_up(v, d);
        if (lane >= d) v += t;
    }
    if (lane == 63) wtot[wid] = v;
    __syncthreads();
    int size = wtot[0] + wtot[1] + wtot[2] + wtot[3];
    bool lds_ok = (size <= CSR_CAP);

    // register edge cache (single global read, exec-masked — no wasted loads)
    int ebuf[RCAP];
#pragma unroll
    for (int i = 0; i < RCAP; ++i)
        if (i < myL) ebuf[i] = pairs[myB + i];

    unsigned lh8 = tid & 7;
    unsigned c0  = lh8 * 8u;

#define EDGE_ACC(S)                                                           \
    { unsigned Su = (unsigned)(S);                                            \
      float Aa = asrc[Su * 8u + lh8] + at;                                    \
      f16x8 Hh = *reinterpret_cast<const f16x8*>(&h[Su * 64u + c0]);          \
      Aa = fmaxf(Aa, NEG_SLOPE * Aa);                                         \
      float Ww = __expf(Aa);                                                  \
      ssum += Ww;                                                             \
      _Pragma("unroll")                                                       \
      for (int i = 0; i < 8; ++i) acc[i] += Ww * (float)Hh[i]; }

#define WRITE_OUT(NODE)                                                       \
    { float inv = 1.f / fmaxf(ssum, EPS_F);                                   \
      float4 b0 = *reinterpret_cast<const float4*>(&bias[c0]);                \
      float4 b1 = *reinterpret_cast<const float4*>(&bias[c0 + 4]);            \
      float4 o0v, o1v;                                                        \
      o0v.x = acc[0] * inv + b0.x; o0v.y = acc[1] * inv + b0.y;               \
      o0v.z = acc[2] * inv + b0.z; o0v.w = acc[3] * inv + b0.w;               \
      o1v.x = acc[4] * inv + b1.x; o1v.y = acc[5] * inv + b1.y;               \
      o1v.z = acc[6] * inv + b1.z; o1v.w = acc[7] * inv + b1.w;               \
      float* op = &out[(size_t)(NODE) * HC + c0];                             \
      *reinterpret_cast<float4*>(op)     = o0v;                               \
      *reinterpret_cast<float4*>(op + 4) = o1v; }

    if (lds_ok) {
        if (tid < BNODES) { hist[tid] = 0; fill[tid] = 0; h2[tid] = 0; }
        __syncthreads();

        // pass A: node-degree histogram from register cache
#pragma unroll
        for (int i = 0; i < RCAP; ++i)
            if (i < myL) atomicAdd(&hist[((unsigned)ebuf[i]) >> 17], 1);
        for (int i = RCAP; i < myL; ++i)
            atomicAdd(&hist[((unsigned)pairs[myB + i]) >> 17], 1);
        __syncthreads();

        // 64-wide node scan in wave 0 (shfl, no barriers)
        int myrank = 0, mybin = 0;
        if (tid < BNODES) {
            int hv = hist[tid];
            int sv = hv;
#pragma unroll
            for (int d = 1; d < 64; d <<= 1) {
                int t = __shfl_up(sv, d);
                if (lane >= d) sv += t;
            }
            scanS[tid] = sv;                       // inclusive
            mybin = min(hv, 63);
            myrank = atomicAdd(&h2[mybin], 1);
        }
        __syncthreads();

        if (tid == 0) {
            int run = 0;
            for (int i = 0; i < 64; ++i) { int t = h2[i]; s2[i] = run; run += t; }
        }
        // pass B: scatter into node-sorted LDS csr (from regs)
#pragma unroll
        for (int i = 0; i < RCAP; ++i)
            if (i < myL) {
                int p = ebuf[i];
                int j = ((unsigned)p) >> 17;
                int r = atomicAdd(&fill[j], 1);
                csrL[scanS[j] - hist[j] + r] = p & 0x1FFFF;
            }
        for (int i = RCAP; i < myL; ++i) {
            int p = pairs[myB + i];
            int j = ((unsigned)p) >> 17;
            int r = atomicAdd(&fill[j], 1);
            csrL[scanS[j] - hist[j] + r] = p & 0x1FFFF;
        }
        __syncthreads();
        if (tid < BNODES) order[s2[mybin] + myrank] = tid;
        __syncthreads();

        // gather: 2 passes x 32 degree-adjacent nodes, 8 lanes/node
        for (int g = 0; g < BNODES; g += 32) {
            int ln   = order[g + (tid >> 3)];
            int node = bN0 + ln;
            if (node >= N) continue;
            int k1 = scanS[ln];
            int k  = k1 - hist[ln];
            float at = atgt[(unsigned)node * 8u + lh8];
            float ssum = 0.f;
            float acc[8] = {0.f, 0.f, 0.f, 0.f, 0.f, 0.f, 0.f, 0.f};

            for (; k + 8 <= k1; k += 8) {
                unsigned S0 = (unsigned)csrL[k],     S1 = (unsigned)csrL[k + 1];
                unsigned S2 = (unsigned)csrL[k + 2], S3 = (unsigned)csrL[k + 3];
                unsigned S4 = (unsigned)csrL[k + 4], S5 = (unsigned)csrL[k + 5];
                unsigned S6 = (unsigned)csrL[k + 6], S7 = (unsigned)csrL[k + 7];
                float A0 = asrc[S0 * 8u + lh8], A1 = asrc[S1 * 8u + lh8];
                float A2 = asrc[S2 * 8u + lh8], A3 = asrc[S3 * 8u + lh8];
                float A4 = asrc[S4 * 8u + lh8], A5 = asrc[S5 * 8u + lh8];
                float A6 = asrc[S6 * 8u + lh8], A7 = asrc[S7 * 8u + lh8];
                f16x8 H0 = *reinterpret_cast<const f16x8*>(&h[S0 * 64u + c0]);
                f16x8 H1 = *reinterpret_cast<const f16x8*>(&h[S1 * 64u + c0]);
                f16x8 H2 = *reinterpret_cast<const f16x8*>(&h[S2 * 64u + c0]);
                f16x8 H3 = *reinterpret_cast<const f16x8*>(&h[S3 * 64u + c0]);
                f16x8 H4 = *reinterpret_cast<const f16x8*>(&h[S4 * 64u + c0]);
                f16x8 H5 = *reinterpret_cast<const f16x8*>(&h[S5 * 64u + c0]);
                f16x8 H6 = *reinterpret_cast<const f16x8*>(&h[S6 * 64u + c0]);
                f16x8 H7 = *reinterpret_cast<const f16x8*>(&h[S7 * 64u + c0]);
                A0 += at; A1 += at; A2 += at; A3 += at;
                A4 += at; A5 += at; A6 += at; A7 += at;
                A0 = fmaxf(A0, NEG_SLOPE * A0); A1 = fmaxf(A1, NEG_SLOPE * A1);
                A2 = fmaxf(A2, NEG_SLOPE * A2); A3 = fmaxf(A3, NEG_SLOPE * A3);
                A4 = fmaxf(A4, NEG_SLOPE * A4); A5 = fmaxf(A5, NEG_SLOPE * A5);
                A6 = fmaxf(A6, NEG_SLOPE * A6); A7 = fmaxf(A7, NEG_SLOPE * A7);
                float w0 = __expf(A0), w1 = __expf(A1);
                float w2 = __expf(A2), w3 = __expf(A3);
                float w4 = __expf(A4), w5 = __expf(A5);
                float w6 = __expf(A6), w7 = __expf(A7);
                ssum += ((w0 + w1) + (w2 + w3)) + ((w4 + w5) + (w6 + w7));
#pragma unroll
                for (int i = 0; i < 8; ++i)
                    acc[i] += ((w0 * (float)H0[i] + w1 * (float)H1[i])
                             + (w2 * (float)H2[i] + w3 * (float)H3[i]))
                            + ((w4 * (float)H4[i] + w5 * (float)H5[i])
                             + (w6 * (float)H6[i] + w7 * (float)H7[i]));
            }
            for (; k < k1; ++k) { EDGE_ACC(csrL[k]); }

            WRITE_OUT(node)
        }
    } else {
        // slow correct fallback: scan all segments per node group (never expected)
        for (int g = 0; g < BNODES; g += 32) {
            int ln   = g + (tid >> 3);
            int node = bN0 + ln;
            if (node >= N) continue;
            float at = atgt[(unsigned)node * 8u + lh8];
            float ssum = 0.f;
            float acc[8] = {0.f, 0.f, 0.f, 0.f, 0.f, 0.f, 0.f, 0.f};
            for (int pb = 0; pb < PBLK; ++pb) {
                int B = segB[pb], L = segL[pb];
                for (int i = 0; i < L; ++i) {
                    int p = pairs[B + i];
                    if ((((unsigned)p) >> 17) == (unsigned)ln) { EDGE_ACC(p & 0x1FFFF); }
                }
            }
            WRITE_OUT(node)
        }
    }
}

extern "C" void kernel_launch(void* const* d_in, const int* in_sizes, int n_in,
                              void* d_out, int out_size, void* d_ws, size_t ws_size,
                              hipStream_t stream)
{
    const float* x    = (const float*)d_in[0];
    const int*   ei   = (const int*)d_in[1];
    const float* W    = (const float*)d_in[2];
    const float* att  = (const float*)d_in[3];
    const float* bias = (const float*)d_in[4];
    float* out = (float*)d_out;

    int N = in_sizes[0] / CIN;
    int E = in_sizes[1] / 2;
    const int* src = ei;
    const int* tgt = ei + E;

    // workspace carve-up (~28 MB)
    f16*   h     = (f16*)d_ws;                    // N*64 fp16       (12.8 MB)
    float* asrc  = (float*)(h + (size_t)N * HC);  // N*8             (3.2 MB)
    float* atgt  = asrc + (size_t)N * 8;          // N*8             (3.2 MB)
    int*   offsT = (int*)(atgt + (size_t)N * 8);  // (NBKT+1)*PBLK   (2.1 MB)
    int*   pairs = offsT + (size_t)(NBKT + 1) * PBLK; // E           (6.4 MB)

    int EPB = (E + PBLK - 1) / PBLK;
    int projB = (N + 127) / 128;

    proj_p3<<<PBLK + projB, 256, 0, stream>>>(x, W, att, h, asrc, atgt, N,
                                              src, tgt, offsT, pairs, E, EPB);

    p4_gather<<<(N + BNODES - 1) / BNODES, 256, 0, stream>>>(
        pairs, offsT, h, asrc, atgt, bias, out, N, E, EPB);
}

// Round 18
// 97.030 us; speedup vs baseline: 1.0253x; 1.0253x over previous
//
#include <hip/hip_runtime.h>
#include <math.h>

#define NEG_SLOPE 0.2f
#define EPS_F 1e-16f
#define CIN 128
#define HC 64
#define BSH 6              // bucket shift: 64 nodes per bucket
#define BNODES 64
#define NBKT 2048          // bucket count (tgt >> 6), max node 131071 (N < 2^17)
#define PBLK 256           // partition blocks
#define CSR_CAP 2048       // LDS csr capacity per bucket (avg ~1025, max ~1200)
#define RCAP 8             // per-thread register edge cache

typedef _Float16 f16;
typedef _Float16 f16x8 __attribute__((ext_vector_type(8)));
typedef float f32x4  __attribute__((ext_vector_type(4)));

// ---- fused: P3 partition (blocks [0,PBLK)) + projection (rest) ------------
// Block-major pairs: block pb owns pairs[pb*EPB ..), sorted by bucket inside.
// offsT is TRANSPOSED: offsT[bkt*PBLK + pb] (scattered writes hidden under
// proj's compute; gives p4 coalesced descriptor reads).
__global__ __launch_bounds__(256) void proj_p3(
    const float* __restrict__ x, const float* __restrict__ W,
    const float* __restrict__ att, f16* __restrict__ h,
    float* __restrict__ asrc, float* __restrict__ atgt, int N,
    const int* __restrict__ src, const int* __restrict__ tgt,
    int* __restrict__ offsT, int* __restrict__ pairs, int E, int EPB)
{
    __shared__ __align__(16) char smem[HC * (CIN + 8) * 2];   // 17408 B union

    if ((int)blockIdx.x < PBLK) {
        // ---- P3 role ----
        int* lh    = (int*)smem;          // [2048] counts -> cursors (8 KB)
        int* scanP = lh + NBKT;           // [256]
        int pb = blockIdx.x, tid = threadIdx.x;
        for (int i = tid; i < NBKT; i += 256) lh[i] = 0;
        __syncthreads();
        int e0 = pb * EPB, e1 = min(E, e0 + EPB), sz = e1 - e0;
        for (int e = e0 + tid; e < e1; e += 256)
            atomicAdd(&lh[((unsigned)tgt[e]) >> BSH], 1);
        __syncthreads();
        // exclusive scan of 2048 bins: 8 bins/thread + 256-wide Hillis-Steele
        int b8 = tid * 8;
        int v[8], s8 = 0;
#pragma unroll
        for (int i = 0; i < 8; ++i) { v[i] = lh[b8 + i]; s8 += v[i]; }
        scanP[tid] = s8;
        __syncthreads();
        for (int d = 1; d < 256; d <<= 1) {
            int t = (tid >= d) ? scanP[tid - d] : 0;
            __syncthreads();
            scanP[tid] += t;
            __syncthreads();
        }
        int base = scanP[tid] - s8;
        __syncthreads();
        {
            int run = base;
#pragma unroll
            for (int i = 0; i < 8; ++i) {
                lh[b8 + i] = run;
                offsT[(size_t)(b8 + i) * PBLK + pb] = run;   // transposed
                run += v[i];
            }
        }
        if (tid == 0) offsT[(size_t)NBKT * PBLK + pb] = sz;
        __syncthreads();
        // scatter within own contiguous region (L2 absorbs in-window RMW)
        for (int e = e0 + tid; e < e1; e += 256) {
            int t = tgt[e];
            int r = atomicAdd(&lh[((unsigned)t) >> BSH], 1);
            pairs[e0 + r] = src[e] | ((t & (BNODES - 1)) << 17);
        }
        return;
    }

    // ---- proj role ----
    f16 (*sWt)[CIN + 8] = (f16(*)[CIN + 8])smem;
    int rowBase = ((int)blockIdx.x - PBLK) * 64;
    for (int i = threadIdx.x; i < CIN * HC; i += 256) {
        int k = i >> 6, c = i & 63;
        sWt[c][k] = (f16)W[i];
    }
    __syncthreads();

    int lane = threadIdx.x & 63;
    int wv   = threadIdx.x >> 6;
    int mrow = lane & 15, g = lane >> 4;
    int r16  = rowBase + wv * 16;

    f16x8 bfrag[4][4];
#pragma unroll
    for (int nt = 0; nt < 4; ++nt)
#pragma unroll
        for (int kc = 0; kc < 4; ++kc)
            bfrag[nt][kc] = *reinterpret_cast<const f16x8*>(&sWt[nt * 16 + mrow][kc * 32 + g * 8]);

    int arow = r16 + mrow;
    const float* xr = x + (size_t)(arow < N ? arow : N - 1) * CIN;
    float4 xa[4][2];
#pragma unroll
    for (int kc = 0; kc < 4; ++kc) {
        xa[kc][0] = *reinterpret_cast<const float4*>(xr + kc * 32 + g * 8);
        xa[kc][1] = *reinterpret_cast<const float4*>(xr + kc * 32 + g * 8 + 4);
    }

    f32x4 acc[4] = {};
#pragma unroll
    for (int kc = 0; kc < 4; ++kc) {
        f16x8 a;
        a[0] = (f16)xa[kc][0].x; a[1] = (f16)xa[kc][0].y;
        a[2] = (f16)xa[kc][0].z; a[3] = (f16)xa[kc][0].w;
        a[4] = (f16)xa[kc][1].x; a[5] = (f16)xa[kc][1].y;
        a[6] = (f16)xa[kc][1].z; a[7] = (f16)xa[kc][1].w;
#pragma unroll
        for (int nt = 0; nt < 4; ++nt)
            acc[nt] = __builtin_amdgcn_mfma_f32_16x16x32_f16(a, bfrag[nt][kc], acc[nt], 0, 0, 0);
    }

#pragma unroll
    for (int nt = 0; nt < 4; ++nt) {
        int c = nt * 16 + mrow;
        float as_w = att[(c >> 3) * 16 + (c & 7)];
        float at_w = att[(c >> 3) * 16 + 8 + (c & 7)];
#pragma unroll
        for (int q = 0; q < 4; ++q) {
            int n = r16 + g * 4 + q;
            float v = acc[nt][q];
            if (n < N) h[(size_t)n * HC + c] = (f16)v;
            float vs = v * as_w, vt = v * at_w;
            vs += __shfl_xor(vs, 1); vs += __shfl_xor(vs, 2); vs += __shfl_xor(vs, 4);
            vt += __shfl_xor(vt, 1); vt += __shfl_xor(vt, 2); vt += __shfl_xor(vt, 4);
            if ((lane & 7) == 0 && n < N) {
                asrc[n * 8 + (c >> 3)] = vs;
                atgt[n * 8 + (c >> 3)] = vt;
            }
        }
    }
}

// ---- fused P4 + gather: reg-cached single-pass segments, shfl scans -------
__global__ __launch_bounds__(256) void p4_gather(
    const int* __restrict__ pairs, const int* __restrict__ offsT,
    const f16* __restrict__ h, const float* __restrict__ asrc,
    const float* __restrict__ atgt, const float* __restrict__ bias,
    float* __restrict__ out, int N, int E, int EPB)
{
    __shared__ int segB[PBLK], segL[PBLK];
    __shared__ int hist[BNODES], scanS[BNODES], fill[BNODES], order[BNODES];
    __shared__ int h2[64], s2[64];
    __shared__ int wtot[4];
    __shared__ int csrL[CSR_CAP];

    int b   = blockIdx.x;
    int tid = threadIdx.x;
    int bN0 = b << BSH;
    int lane = tid & 63, wid = tid >> 6;

    // coalesced descriptor reads (transposed offs)
    int o0 = offsT[(size_t)b * PBLK + tid];
    int o1 = offsT[(size_t)(b + 1) * PBLK + tid];
    int myB = tid * EPB + o0;
    int myL = o1 - o0;
    segB[tid] = myB;
    segL[tid] = myL;

    // 256-wide exclusive scan of myL: shfl within wave + cross-wave fixup
    int v = myL;
#pragma unroll
    for (int d = 1; d < 64; d <<= 1) {
        int t = __shfl_up(v, d);
        if (lane >= d) v += t;
    }
    if (lane == 63) wtot[wid] = v;
    __syncthreads();
    int pre = 0;
#pragma unroll
    for (int w = 0; w < 4; ++w) pre += (w < wid) ? wtot[w] : 0;
    int size = wtot[0] + wtot[1] + wtot[2] + wtot[3];
    int myO  = v + pre - myL;
    bool lds_ok = (size <= CSR_CAP);

    // register edge cache (single global read of the segment)
    int ebuf[RCAP];
    {
        int Emax = E - 1;
#pragma unroll
        for (int i = 0; i < RCAP; ++i) {
            int idx = myB + ((i < myL) ? i : 0);
            ebuf[i] = pairs[min(idx, Emax)];
        }
    }

    unsigned lh8 = tid & 7;
    unsigned c0  = lh8 * 8u;

#define EDGE_ACC(S)                                                           \
    { unsigned Su = (unsigned)(S);                                            \
      float Aa = asrc[Su * 8u + lh8] + at;                                    \
      f16x8 Hh = *reinterpret_cast<const f16x8*>(&h[Su * 64u + c0]);          \
      Aa = fmaxf(Aa, NEG_SLOPE * Aa);                                         \
      float Ww = __expf(Aa);                                                  \
      ssum += Ww;                                                             \
      _Pragma("unroll")                                                       \
      for (int i = 0; i < 8; ++i) acc[i] += Ww * (float)Hh[i]; }

#define WRITE_OUT(NODE)                                                       \
    { float inv = 1.f / fmaxf(ssum, EPS_F);                                   \
      float4 b0 = *reinterpret_cast<const float4*>(&bias[c0]);                \
      float4 b1 = *reinterpret_cast<const float4*>(&bias[c0 + 4]);            \
      float4 o0v, o1v;                                                        \
      o0v.x = acc[0] * inv + b0.x; o0v.y = acc[1] * inv + b0.y;               \
      o0v.z = acc[2] * inv + b0.z; o0v.w = acc[3] * inv + b0.w;               \
      o1v.x = acc[4] * inv + b1.x; o1v.y = acc[5] * inv + b1.y;               \
      o1v.z = acc[6] * inv + b1.z; o1v.w = acc[7] * inv + b1.w;               \
      float* op = &out[(size_t)(NODE) * HC + c0];                             \
      *reinterpret_cast<float4*>(op)     = o0v;                               \
      *reinterpret_cast<float4*>(op + 4) = o1v; }

    if (lds_ok) {
        if (tid < BNODES) { hist[tid] = 0; fill[tid] = 0; h2[tid] = 0; }
        __syncthreads();

        // pass A: node-degree histogram from register cache
#pragma unroll
        for (int i = 0; i < RCAP; ++i)
            if (i < myL) atomicAdd(&hist[((unsigned)ebuf[i]) >> 17], 1);
        for (int i = RCAP; i < myL; ++i)
            atomicAdd(&hist[((unsigned)pairs[myB + i]) >> 17], 1);
        __syncthreads();

        // 64-wide node scan in wave 0 (shfl, no barriers)
        int myrank = 0, mybin = 0;
        if (tid < BNODES) {
            int hv = hist[tid];
            int sv = hv;
#pragma unroll
            for (int d = 1; d < 64; d <<= 1) {
                int t = __shfl_up(sv, d);
                if (lane >= d) sv += t;
            }
            scanS[tid] = sv;                       // inclusive
            mybin = min(hv, 63);
            myrank = atomicAdd(&h2[mybin], 1);
        }
        __syncthreads();

        if (tid == 0) {
            int run = 0;
            for (int i = 0; i < 64; ++i) { int t = h2[i]; s2[i] = run; run += t; }
        }
        // pass B: scatter into node-sorted LDS csr (from regs)
#pragma unroll
        for (int i = 0; i < RCAP; ++i)
            if (i < myL) {
                int p = ebuf[i];
                int j = ((unsigned)p) >> 17;
                int r = atomicAdd(&fill[j], 1);
                csrL[scanS[j] - hist[j] + r] = p & 0x1FFFF;
            }
        for (int i = RCAP; i < myL; ++i) {
            int p = pairs[myB + i];
            int j = ((unsigned)p) >> 17;
            int r = atomicAdd(&fill[j], 1);
            csrL[scanS[j] - hist[j] + r] = p & 0x1FFFF;
        }
        __syncthreads();
        if (tid < BNODES) order[s2[mybin] + myrank] = tid;
        __syncthreads();

        // gather: 2 passes x 32 degree-adjacent nodes, 8 lanes/node
        for (int g = 0; g < BNODES; g += 32) {
            int ln   = order[g + (tid >> 3)];
            int node = bN0 + ln;
            if (node >= N) continue;
            int k1 = scanS[ln];
            int k  = k1 - hist[ln];
            float at = atgt[(unsigned)node * 8u + lh8];
            float ssum = 0.f;
            float acc[8] = {0.f, 0.f, 0.f, 0.f, 0.f, 0.f, 0.f, 0.f};

            for (; k + 8 <= k1; k += 8) {
                unsigned S0 = (unsigned)csrL[k],     S1 = (unsigned)csrL[k + 1];
                unsigned S2 = (unsigned)csrL[k + 2], S3 = (unsigned)csrL[k + 3];
                unsigned S4 = (unsigned)csrL[k + 4], S5 = (unsigned)csrL[k + 5];
                unsigned S6 = (unsigned)csrL[k + 6], S7 = (unsigned)csrL[k + 7];
                float A0 = asrc[S0 * 8u + lh8], A1 = asrc[S1 * 8u + lh8];
                float A2 = asrc[S2 * 8u + lh8], A3 = asrc[S3 * 8u + lh8];
                float A4 = asrc[S4 * 8u + lh8], A5 = asrc[S5 * 8u + lh8];
                float A6 = asrc[S6 * 8u + lh8], A7 = asrc[S7 * 8u + lh8];
                f16x8 H0 = *reinterpret_cast<const f16x8*>(&h[S0 * 64u + c0]);
                f16x8 H1 = *reinterpret_cast<const f16x8*>(&h[S1 * 64u + c0]);
                f16x8 H2 = *reinterpret_cast<const f16x8*>(&h[S2 * 64u + c0]);
                f16x8 H3 = *reinterpret_cast<const f16x8*>(&h[S3 * 64u + c0]);
                f16x8 H4 = *reinterpret_cast<const f16x8*>(&h[S4 * 64u + c0]);
                f16x8 H5 = *reinterpret_cast<const f16x8*>(&h[S5 * 64u + c0]);
                f16x8 H6 = *reinterpret_cast<const f16x8*>(&h[S6 * 64u + c0]);
                f16x8 H7 = *reinterpret_cast<const f16x8*>(&h[S7 * 64u + c0]);
                A0 += at; A1 += at; A2 += at; A3 += at;
                A4 += at; A5 += at; A6 += at; A7 += at;
                A0 = fmaxf(A0, NEG_SLOPE * A0); A1 = fmaxf(A1, NEG_SLOPE * A1);
                A2 = fmaxf(A2, NEG_SLOPE * A2); A3 = fmaxf(A3, NEG_SLOPE * A3);
                A4 = fmaxf(A4, NEG_SLOPE * A4); A5 = fmaxf(A5, NEG_SLOPE * A5);
                A6 = fmaxf(A6, NEG_SLOPE * A6); A7 = fmaxf(A7, NEG_SLOPE * A7);
                float w0 = __expf(A0), w1 = __expf(A1);
                float w2 = __expf(A2), w3 = __expf(A3);
                float w4 = __expf(A4), w5 = __expf(A5);
                float w6 = __expf(A6), w7 = __expf(A7);
                ssum += ((w0 + w1) + (w2 + w3)) + ((w4 + w5) + (w6 + w7));
#pragma unroll
                for (int i = 0; i < 8; ++i)
                    acc[i] += ((w0 * (float)H0[i] + w1 * (float)H1[i])
                             + (w2 * (float)H2[i] + w3 * (float)H3[i]))
                            + ((w4 * (float)H4[i] + w5 * (float)H5[i])
                             + (w6 * (float)H6[i] + w7 * (float)H7[i]));
            }
            for (; k < k1; ++k) { EDGE_ACC(csrL[k]); }

            WRITE_OUT(node)
        }
    } else {
        // slow correct fallback: scan all segments per node group (never expected)
        for (int g = 0; g < BNODES; g += 32) {
            int ln   = g + (tid >> 3);
            int node = bN0 + ln;
            if (node >= N) continue;
            float at = atgt[(unsigned)node * 8u + lh8];
            float ssum = 0.f;
            float acc[8] = {0.f, 0.f, 0.f, 0.f, 0.f, 0.f, 0.f, 0.f};
            for (int pb = 0; pb < PBLK; ++pb) {
                int B = segB[pb], L = segL[pb];
                for (int i = 0; i < L; ++i) {
                    int p = pairs[B + i];
                    if ((((unsigned)p) >> 17) == (unsigned)ln) { EDGE_ACC(p & 0x1FFFF); }
                }
            }
            WRITE_OUT(node)
        }
    }
}

extern "C" void kernel_launch(void* const* d_in, const int* in_sizes, int n_in,
                              void* d_out, int out_size, void* d_ws, size_t ws_size,
                              hipStream_t stream)
{
    const float* x    = (const float*)d_in[0];
    const int*   ei   = (const int*)d_in[1];
    const float* W    = (const float*)d_in[2];
    const float* att  = (const float*)d_in[3];
    const float* bias = (const float*)d_in[4];
    float* out = (float*)d_out;

    int N = in_sizes[0] / CIN;
    int E = in_sizes[1] / 2;
    const int* src = ei;
    const int* tgt = ei + E;

    // workspace carve-up (~28 MB)
    f16*   h     = (f16*)d_ws;                    // N*64 fp16       (12.8 MB)
    float* asrc  = (float*)(h + (size_t)N * HC);  // N*8             (3.2 MB)
    float* atgt  = asrc + (size_t)N * 8;          // N*8             (3.2 MB)
    int*   offsT = (int*)(atgt + (size_t)N * 8);  // (NBKT+1)*PBLK   (2.1 MB)
    int*   pairs = offsT + (size_t)(NBKT + 1) * PBLK; // E           (6.4 MB)

    int EPB = (E + PBLK - 1) / PBLK;
    int projB = (N + 63) / 64;

    proj_p3<<<PBLK + projB, 256, 0, stream>>>(x, W, att, h, asrc, atgt, N,
                                              src, tgt, offsT, pairs, E, EPB);

    p4_gather<<<(N + BNODES - 1) / BNODES, 256, 0, stream>>>(
        pairs, offsT, h, asrc, atgt, bias, out, N, E, EPB);
}